// Round 2
// baseline (1597.086 us; speedup 1.0000x reference)
//
#include <hip/hip_runtime.h>
#include <math.h>

#define NB 16    // batch
#define SS 256   // spatial size (H = W = 256)
#define DV 32    // channels
#define MM 12    // ky modes kept
#define MK 24    // kx modes kept (0..11 and 244..255)
#define LL 4     // layers

// Workspace layout (floats):
//   h : [NB][DV][SS][SS]              (in-place updated per layer)
//   A : [NB][MM(ky)][DV][SS(iy)][2]   (forward ky-DFT of h rows)
//   g : [NB][MM(ky)][DV][SS(iy)][2]   (inverse kx-DFT of mixed modes)

__device__ __forceinline__ void make_tw(float* tw_c, float* tw_s) {
    int tid = threadIdx.x;
    float ang = 0.024543692606170259679f * (float)tid;  // 2*pi/256
    float s, c;
    sincosf(ang, &s, &c);
    tw_c[tid] = c;
    tw_s[tid] = s;
}

// Fused row -> A ky-DFT. Thread t handles c = t>>3, 32 columns starting at
// (t&7)*32. Twiddles via register phasor recurrence (exact LDS-table start);
// 8-lane shfl_xor reduction; float2 stores.
__device__ __forceinline__ void row_dft_store(const float row[DV][SS + 4],
        const float* tw_c, const float* tw_s,
        float* __restrict__ A, int b, int iy, int tid)
{
    int c  = tid >> 3;
    int ch = tid & 7;
    int j0 = ch * 32;

    float ar[MM], ai[MM], pr[MM], pi[MM], sr[MM], si[MM];
    #pragma unroll
    for (int ky = 0; ky < MM; ++ky) {
        ar[ky] = 0.f; ai[ky] = 0.f;
        int t0 = (ky * j0) & 255;
        pr[ky] = tw_c[t0]; pi[ky] = -tw_s[t0];   // e^{-i w ky j0}
        sr[ky] = tw_c[ky]; si[ky] = -tw_s[ky];   // e^{-i w ky}
    }

    #pragma unroll 1
    for (int k = 0; k < 8; ++k) {
        float4 q = *(const float4*)&row[c][j0 + 4 * k];
        float vv[4] = {q.x, q.y, q.z, q.w};
        #pragma unroll
        for (int u = 0; u < 4; ++u) {
            float v = vv[u];
            #pragma unroll
            for (int ky = 0; ky < MM; ++ky) {
                ar[ky] += v * pr[ky];
                ai[ky] += v * pi[ky];
                float nr = pr[ky] * sr[ky] - pi[ky] * si[ky];
                float ni = pr[ky] * si[ky] + pi[ky] * sr[ky];
                pr[ky] = nr; pi[ky] = ni;
            }
        }
    }

    // reduce over the 8 lanes sharing c (adjacent lanes, xor 1/2/4)
    #pragma unroll
    for (int m = 1; m < 8; m <<= 1) {
        #pragma unroll
        for (int ky = 0; ky < MM; ++ky) {
            ar[ky] += __shfl_xor(ar[ky], m, 64);
            ai[ky] += __shfl_xor(ai[ky], m, 64);
        }
    }

    for (int ky = ch; ky < MM; ky += 8) {
        size_t o = ((((size_t)b * MM + ky) * DV + c) * SS + iy) * 2;
        float2 val; val.x = ar[ky]; val.y = ai[ky];
        *(float2*)&A[o] = val;
    }
}

// Lifting: h0[b,c,iy,j] = p_w[c,0]*x + p_w[c,1]*gy(iy) + p_w[c,2]*gx(j) + p_b[c]
// Also emits A0 = ky-DFT of each row.
__global__ __launch_bounds__(256) void k_lift(const float* __restrict__ x,
        const float* __restrict__ p_w, const float* __restrict__ p_b,
        float* __restrict__ h, float* __restrict__ A)
{
    __shared__ float row[DV][SS + 4];
    __shared__ float tw_c[SS], tw_s[SS];
    int tid = threadIdx.x;
    int b  = blockIdx.x >> 8;
    int iy = blockIdx.x & 255;
    make_tw(tw_c, tw_s);

    float xv = x[((size_t)b * SS + iy) * SS + tid];
    float gy = -1.0f + 2.0f * (float)iy  * (1.0f / 255.0f);
    float gx = -1.0f + 2.0f * (float)tid * (1.0f / 255.0f);

    float* hb = h + ((size_t)b * DV * SS + iy) * SS;
    for (int c = 0; c < DV; ++c) {
        float v = p_w[3*c] * xv + p_w[3*c + 1] * gy + p_w[3*c + 2] * gx + p_b[c];
        row[c][tid] = v;
        hb[(size_t)c * SS * SS + tid] = v;
    }
    __syncthreads();

    row_dft_store(row, tw_c, tw_s, A, b, iy, tid);
}

// Per (b,ky): kx-DFT over iy (24 modes) -> channel mix with W1/W2 -> inverse kx-DFT.
__global__ __launch_bounds__(256) void k_modes(const float* __restrict__ A,
        const float* __restrict__ w1r, const float* __restrict__ w1i,
        const float* __restrict__ w2r, const float* __restrict__ w2i,
        float* __restrict__ g, int l)
{
    __shared__ float Abuf[DV][SS * 2 + 2];
    __shared__ float Fin[DV][MK * 2];
    __shared__ float Fout[DV][MK * 2];
    __shared__ float tw_c[SS], tw_s[SS];
    int tid = threadIdx.x;
    int b  = blockIdx.x / MM;
    int ky = blockIdx.x % MM;
    make_tw(tw_c, tw_s);

    const float* Ab = A + (((size_t)b * MM + ky) * DV) * SS * 2;
    for (int k = tid; k < DV * SS * 2; k += 256) {
        int c = k >> 9;
        int r = k & 511;
        Abuf[c][r] = Ab[k];
    }
    __syncthreads();

    // forward DFT along h:  F = sum_iy A * e^{-i 2pi f iy/256}
    for (int idx = tid; idx < DV * MK; idx += 256) {
        int c = idx / MK, m = idx % MK;
        int freq = (m < MM) ? m : (232 + m);   // 244..255 for m=12..23
        float fr = 0.f, fi = 0.f;
        for (int iy = 0; iy < SS; ++iy) {
            int t = (freq * iy) & 255;
            float ar = Abuf[c][iy * 2], ai = Abuf[c][iy * 2 + 1];
            float cc = tw_c[t], sn = tw_s[t];
            fr += ar * cc + ai * sn;
            fi += ai * cc - ar * sn;
        }
        Fin[c][m * 2] = fr; Fin[c][m * 2 + 1] = fi;
    }
    __syncthreads();

    // channel mixing: out[o] = sum_i F[i] * W[i,o]   (complex)
    float scale = ((ky == 0) ? 1.0f : 2.0f) * (1.0f / 65536.0f);
    for (int idx = tid; idx < DV * MK; idx += 256) {
        int o = idx / MK, m = idx % MK;
        const float* Wr; const float* Wi; int xm;
        if (m < MM) { Wr = w1r; Wi = w1i; xm = m; }
        else        { Wr = w2r; Wi = w2i; xm = m - MM; }
        size_t wbase = ((size_t)l * DV * DV + o) * (MM * MM) + xm * MM + ky;
        float orr = 0.f, oii = 0.f;
        for (int i = 0; i < DV; ++i) {
            float fr = Fin[i][m * 2], fi = Fin[i][m * 2 + 1];
            size_t wi = wbase + (size_t)i * DV * MM * MM;
            float wr = Wr[wi], wim = Wi[wi];
            orr += fr * wr - fi * wim;
            oii += fr * wim + fi * wr;
        }
        Fout[o][m * 2] = orr * scale;
        Fout[o][m * 2 + 1] = oii * scale;
    }
    __syncthreads();

    // inverse DFT along h: g = sum_m Fout * e^{+i 2pi f iy/256}
    float* gb = g + (((size_t)b * MM + ky) * DV) * SS * 2;
    for (int idx = tid; idx < DV * SS; idx += 256) {
        int c = idx >> 8, iy = idx & 255;
        float gr = 0.f, gi = 0.f;
        #pragma unroll
        for (int m = 0; m < MK; ++m) {
            int freq = (m < MM) ? m : (232 + m);
            int t = (freq * iy) & 255;
            float cc = tw_c[t], sn = tw_s[t];
            float fr = Fout[c][m * 2], fi = Fout[c][m * 2 + 1];
            gr += fr * cc - fi * sn;
            gi += fr * sn + fi * cc;
        }
        gb[((size_t)c * SS + iy) * 2]     = gr;
        gb[((size_t)c * SS + iy) * 2 + 1] = gi;
    }
}

// One block per (b,row): h_next = relu( conv1x1(h) + irfft_w(g) ), in place.
// Also emits next layer's A (ky-DFT of the new row).
template<bool RELU>
__global__ __launch_bounds__(256) void k_layer(float* __restrict__ h,
        const float* __restrict__ g, const float* __restrict__ ws_w,
        const float* __restrict__ ws_b, float* __restrict__ A, int l)
{
    __shared__ float row[DV][SS + 4];
    __shared__ float tw_c[SS], tw_s[SS];
    int tid = threadIdx.x;
    int b  = blockIdx.x >> 8;
    int iy = blockIdx.x & 255;
    make_tw(tw_c, tw_s);

    float* hb = h + ((size_t)b * DV * SS + iy) * SS;
    float hval[DV];
    #pragma unroll
    for (int c = 0; c < DV; ++c)
        hval[c] = hb[(size_t)c * SS * SS + tid];
    __syncthreads();  // tw table ready

    float cs[MM], sn[MM];
    #pragma unroll
    for (int ky = 0; ky < MM; ++ky) {
        int t = (ky * tid) & 255;
        cs[ky] = tw_c[t]; sn[ky] = tw_s[t];
    }

    const float* gb  = g + (size_t)b * MM * DV * SS * 2;   // [ky][c][iy][2]
    const float* wsw = ws_w + (size_t)l * DV * DV;
    const float* wsb = ws_b + (size_t)l * DV;

    for (int co = 0; co < DV; ++co) {
        float acc = wsb[co];
        #pragma unroll
        for (int ci = 0; ci < DV; ++ci)
            acc += wsw[co * DV + ci] * hval[ci];   // uniform -> scalar loads
        #pragma unroll
        for (int ky = 0; ky < MM; ++ky) {
            float gr = gb[(((size_t)ky * DV + co) * SS + iy) * 2];
            float gi = gb[(((size_t)ky * DV + co) * SS + iy) * 2 + 1];
            acc += gr * cs[ky] - gi * sn[ky];
        }
        if (RELU) acc = fmaxf(acc, 0.f);
        row[co][tid] = acc;
        hb[(size_t)co * SS * SS + tid] = acc;
    }
    __syncthreads();

    row_dft_store(row, tw_c, tw_s, A, b, iy, tid);
}

// Last layer fused with projection: out = q_b + sum_co q_w[co]*(conv+irfft)  (no relu)
__global__ __launch_bounds__(256) void k_final(const float* __restrict__ h,
        const float* __restrict__ g, const float* __restrict__ ws_w,
        const float* __restrict__ ws_b, const float* __restrict__ q_w,
        const float* __restrict__ q_b, float* __restrict__ out, int l)
{
    __shared__ float tw_c[SS], tw_s[SS];
    int tid = threadIdx.x;
    int b  = blockIdx.x >> 8;
    int iy = blockIdx.x & 255;
    make_tw(tw_c, tw_s);

    const float* hb = h + ((size_t)b * DV * SS + iy) * SS;
    float hval[DV];
    #pragma unroll
    for (int c = 0; c < DV; ++c)
        hval[c] = hb[(size_t)c * SS * SS + tid];
    __syncthreads();

    float cs[MM], sn[MM];
    #pragma unroll
    for (int ky = 0; ky < MM; ++ky) {
        int t = (ky * tid) & 255;
        cs[ky] = tw_c[t]; sn[ky] = tw_s[t];
    }

    const float* gb  = g + (size_t)b * MM * DV * SS * 2;
    const float* wsw = ws_w + (size_t)l * DV * DV;
    const float* wsb = ws_b + (size_t)l * DV;

    float oacc = q_b[0];
    for (int co = 0; co < DV; ++co) {
        float acc = wsb[co];
        #pragma unroll
        for (int ci = 0; ci < DV; ++ci)
            acc += wsw[co * DV + ci] * hval[ci];
        #pragma unroll
        for (int ky = 0; ky < MM; ++ky) {
            float gr = gb[(((size_t)ky * DV + co) * SS + iy) * 2];
            float gi = gb[(((size_t)ky * DV + co) * SS + iy) * 2 + 1];
            acc += gr * cs[ky] - gi * sn[ky];
        }
        oacc += q_w[co] * acc;
    }
    out[((size_t)b * SS + iy) * SS + tid] = oacc;
}

extern "C" void kernel_launch(void* const* d_in, const int* in_sizes, int n_in,
                              void* d_out, int out_size, void* d_ws, size_t ws_size,
                              hipStream_t stream)
{
    const float* x    = (const float*)d_in[0];
    const float* p_w  = (const float*)d_in[1];
    const float* p_b  = (const float*)d_in[2];
    const float* ws_w = (const float*)d_in[3];
    const float* ws_b = (const float*)d_in[4];
    const float* w1r  = (const float*)d_in[5];
    const float* w1i  = (const float*)d_in[6];
    const float* w2r  = (const float*)d_in[7];
    const float* w2i  = (const float*)d_in[8];
    const float* q_w  = (const float*)d_in[9];
    const float* q_b  = (const float*)d_in[10];
    float* out = (float*)d_out;

    float* h = (float*)d_ws;
    float* A = h + (size_t)NB * DV * SS * SS;
    float* g = A + (size_t)NB * MM * DV * SS * 2;

    dim3 blk(256);
    k_lift<<<NB * SS, blk, 0, stream>>>(x, p_w, p_b, h, A);
    for (int l = 0; l < LL; ++l) {
        k_modes<<<NB * MM, blk, 0, stream>>>(A, w1r, w1i, w2r, w2i, g, l);
        if (l < LL - 1)
            k_layer<true><<<NB * SS, blk, 0, stream>>>(h, g, ws_w, ws_b, A, l);
        else
            k_final<<<NB * SS, blk, 0, stream>>>(h, g, ws_w, ws_b, q_w, q_b, out, l);
    }
}

// Round 3
// 1030.458 us; speedup vs baseline: 1.5499x; 1.5499x over previous
//
#include <hip/hip_runtime.h>
#include <math.h>

#define NB 16    // batch
#define SS 256   // spatial size (H = W = 256)
#define DV 32    // channels
#define MM 12    // w-dim (j) modes kept
#define MK 24    // h-dim (iy) modes kept (0..11 and 244..255)
#define LL 4     // layers
#define TWO_PI_N 0.024543692606170259679f   // 2*pi/256

// Workspace (floats):
//   h : [NB][DV][SS][SS]            134 MB, in-place per layer
//   A : [NB][MM][DV][SS(iy)][2]     12.6 MB  (row-DFT of h)
//   F : [NB][MM][DV][MK][2]          1.2 MB  (mixed spectral coeffs, pre-scaled)

// ---------------------------------------------------------------- lifting
__global__ __launch_bounds__(256) void k_lift(const float* __restrict__ x,
        const float* __restrict__ p_w, const float* __restrict__ p_b,
        float* __restrict__ h)
{
    int tid = threadIdx.x;
    int b = blockIdx.x >> 8, iy = blockIdx.x & 255;
    float xv = x[((size_t)b * SS + iy) * SS + tid];
    float gy = -1.f + 2.f * (float)iy  * (1.f / 255.f);
    float gx = -1.f + 2.f * (float)tid * (1.f / 255.f);
    float* hb = h + ((size_t)b * DV * SS + iy) * SS + tid;
    #pragma unroll
    for (int c = 0; c < DV; ++c)
        hb[(size_t)c * SS * SS] = p_w[3*c] * xv + p_w[3*c+1] * gy
                                + p_w[3*c+2] * gx + p_b[c];
}

// ------------------------------------------------- forward row (j) DFT, 12 modes
// block = (b,c); lane = iy; thread owns its entire row in the j-loop.
// Twiddle table [j][ky][2] = (cos, -sin) in LDS; reads are wave-uniform b128.
__global__ __launch_bounds__(256) void k_rowdft(const float* __restrict__ h,
        float* __restrict__ A)
{
    __shared__ float twA[SS * MM * 2];   // 24 KB
    int tid = threadIdx.x;
    int b = blockIdx.x >> 5, c = blockIdx.x & 31;

    for (int idx = tid; idx < SS * MM; idx += 256) {
        int j = idx / MM, ky = idx % MM;
        float ang = TWO_PI_N * (float)((ky * j) & 255);
        float s, cc; sincosf(ang, &s, &cc);
        twA[idx * 2] = cc; twA[idx * 2 + 1] = -s;
    }
    __syncthreads();

    const float4* hr = (const float4*)(h + ((size_t)blockIdx.x * SS + tid) * SS);
    float ar[MM], ai[MM];
    #pragma unroll
    for (int k = 0; k < MM; ++k) { ar[k] = 0.f; ai[k] = 0.f; }

    for (int j4 = 0; j4 < 64; ++j4) {
        float4 v = hr[j4];
        float vv[4] = {v.x, v.y, v.z, v.w};
        #pragma unroll
        for (int u = 0; u < 4; ++u) {
            const float4* tw4 = (const float4*)&twA[(4 * j4 + u) * MM * 2];
            float vu = vv[u];
            #pragma unroll
            for (int q = 0; q < 6; ++q) {          // 2 modes per float4
                float4 w = tw4[q];
                ar[2*q]   += vu * w.x; ai[2*q]   += vu * w.y;
                ar[2*q+1] += vu * w.z; ai[2*q+1] += vu * w.w;
            }
        }
    }
    #pragma unroll
    for (int ky = 0; ky < MM; ++ky) {
        size_t o = ((((size_t)b * MM + ky) * DV + c) * SS + tid) * 2;
        float2 val; val.x = ar[ky]; val.y = ai[ky];
        *(float2*)&A[o] = val;                      // coalesced over iy
    }
}

// --------------------------- kx (iy) DFT + complex channel mix -> F (pre-scaled)
// block = (b,ky). Phase 1: thread = (c, m-set of 3), register phasors with
// LDS-table re-anchor every 64 steps. Phase 2: mix over 32 input channels.
__global__ __launch_bounds__(256) void k_mix(const float* __restrict__ A,
        const float* __restrict__ w1r, const float* __restrict__ w1i,
        const float* __restrict__ w2r, const float* __restrict__ w2i,
        float* __restrict__ F, int l)
{
    __shared__ float twcs[SS * 2];             // (cos, sin) of +2*pi*t/256
    __shared__ float Fin[DV][MK * 2 + 2];
    int tid = threadIdx.x;
    int b = blockIdx.x / MM, ky = blockIdx.x % MM;
    {
        float ang = TWO_PI_N * (float)tid;
        float s, c; sincosf(ang, &s, &c);
        twcs[2 * tid] = c; twcs[2 * tid + 1] = s;
    }
    __syncthreads();

    int c = tid >> 3, set = tid & 7;
    const float2* Ap = (const float2*)(A + ((((size_t)b * MM + ky) * DV + c) * SS) * 2);

    float fr[3], fi[3], pc[3], ps[3], sc[3], ssn[3];
    int f[3];
    #pragma unroll
    for (int k = 0; k < 3; ++k) {
        int m = set + 8 * k;
        f[k] = (m < MM) ? m : (232 + m);       // 244..255 for m >= 12
        sc[k] = twcs[2 * f[k]]; ssn[k] = twcs[2 * f[k] + 1];
        fr[k] = fi[k] = 0.f; pc[k] = 1.f; ps[k] = 0.f;
    }
    for (int iy = 0; iy < SS; ++iy) {
        if ((iy & 63) == 0) {                  // re-anchor: kills phasor drift
            #pragma unroll
            for (int k = 0; k < 3; ++k) {
                int t = (f[k] * iy) & 255;
                pc[k] = twcs[2 * t]; ps[k] = twcs[2 * t + 1];
            }
        }
        float2 a = Ap[iy];
        #pragma unroll
        for (int k = 0; k < 3; ++k) {
            fr[k] += a.x * pc[k] + a.y * ps[k];   // A * e^{-i th}
            fi[k] += a.y * pc[k] - a.x * ps[k];
            float np = pc[k] * sc[k] - ps[k] * ssn[k];
            float nq = pc[k] * ssn[k] + ps[k] * sc[k];
            pc[k] = np; ps[k] = nq;
        }
    }
    #pragma unroll
    for (int k = 0; k < 3; ++k) {
        int m = set + 8 * k;
        Fin[c][2 * m] = fr[k]; Fin[c][2 * m + 1] = fi[k];
    }
    __syncthreads();

    int o = c;
    float scale = ((ky == 0) ? 1.0f : 2.0f) * (1.0f / 65536.0f);
    #pragma unroll
    for (int k = 0; k < 3; ++k) {
        int m = set + 8 * k;
        const float* Wr; const float* Wi; int xm;
        if (m < MM) { Wr = w1r; Wi = w1i; xm = m; }
        else        { Wr = w2r; Wi = w2i; xm = m - MM; }
        float orr = 0.f, oii = 0.f;
        for (int i = 0; i < DV; ++i) {
            float gr = Fin[i][2 * m], gi = Fin[i][2 * m + 1];
            size_t wi = ((size_t)(l * DV + i) * DV + o) * (MM * MM) + xm * MM + ky;
            float wr = Wr[wi], wim = Wi[wi];
            orr += gr * wr - gi * wim;
            oii += gr * wim + gi * wr;
        }
        size_t off = ((((size_t)b * MM + ky) * DV + o) * MK + m) * 2;
        F[off] = orr * scale; F[off + 1] = oii * scale;
    }
}

// ----------------- pointwise: h = relu(conv1x1(h) + invDFT(F)), in place.
// block = (b,iy); builds the 3 KB g-row from F in-block (inverse iy-DFT with
// wave-uniform twiddles), then conv + inverse j-DFT per output channel.
template<int FINAL>
__global__ __launch_bounds__(256) void k_pt(float* __restrict__ h,
        const float* __restrict__ F, const float* __restrict__ ws_w,
        const float* __restrict__ ws_b, const float* __restrict__ q_w,
        const float* __restrict__ q_b, float* __restrict__ out, int l)
{
    __shared__ float gS[DV][MM * 2];   // [co][ky][2], rows 96 B -> b128-aligned
    __shared__ float itw[MK * 2];      // e^{+i 2pi f_m iy/256}
    int tid = threadIdx.x;
    int b = blockIdx.x >> 8, iy = blockIdx.x & 255;

    if (tid < MK) {
        int f = (tid < MM) ? tid : (232 + tid);
        float ang = TWO_PI_N * (float)((f * iy) & 255);
        float s, c; sincosf(ang, &s, &c);
        itw[2 * tid] = c; itw[2 * tid + 1] = s;
    }

    float* hb = h + ((size_t)b * DV * SS + iy) * SS + tid;
    float hval[DV];
    #pragma unroll
    for (int cc = 0; cc < DV; ++cc)
        hval[cc] = hb[(size_t)cc * SS * SS];

    float cs[MM], sn[MM];                      // e^{+i 2pi ky j/256}, j = tid
    #pragma unroll
    for (int ky = 0; ky < MM; ++ky) {
        float ang = TWO_PI_N * (float)((ky * tid) & 255);
        sincosf(ang, &sn[ky], &cs[ky]);
    }
    __syncthreads();                            // itw ready

    for (int idx = tid; idx < DV * MM; idx += 256) {
        int co = idx & 31, ky = idx >> 5;
        const float2* Fp = (const float2*)(F + ((((size_t)b * MM + ky) * DV + co) * MK) * 2);
        float gr = 0.f, gi = 0.f;
        #pragma unroll
        for (int m = 0; m < MK; ++m) {
            float2 fv = Fp[m];
            float ic = itw[2 * m], is = itw[2 * m + 1];
            gr += fv.x * ic - fv.y * is;        // F * e^{+i th}
            gi += fv.x * is + fv.y * ic;
        }
        gS[co][2 * ky] = gr; gS[co][2 * ky + 1] = gi;
    }
    __syncthreads();

    const float* wsw = ws_w + (size_t)l * DV * DV;
    const float* wsb = ws_b + (size_t)l * DV;
    float oacc = FINAL ? q_b[0] : 0.f;

    #pragma unroll 4
    for (int co = 0; co < DV; ++co) {
        float acc = wsb[co];
        #pragma unroll
        for (int ci = 0; ci < DV; ++ci)
            acc += wsw[co * DV + ci] * hval[ci];        // scalar weights
        const float4* gp = (const float4*)&gS[co][0];   // broadcast b128
        #pragma unroll
        for (int q = 0; q < 6; ++q) {
            float4 gv = gp[q];
            acc += gv.x * cs[2*q]   - gv.y * sn[2*q];
            acc += gv.z * cs[2*q+1] - gv.w * sn[2*q+1];
        }
        if (FINAL) oacc += q_w[co] * acc;
        else       hb[(size_t)co * SS * SS] = fmaxf(acc, 0.f);
    }
    if (FINAL) out[((size_t)b * SS + iy) * SS + tid] = oacc;
}

extern "C" void kernel_launch(void* const* d_in, const int* in_sizes, int n_in,
                              void* d_out, int out_size, void* d_ws, size_t ws_size,
                              hipStream_t stream)
{
    const float* x    = (const float*)d_in[0];
    const float* p_w  = (const float*)d_in[1];
    const float* p_b  = (const float*)d_in[2];
    const float* ws_w = (const float*)d_in[3];
    const float* ws_b = (const float*)d_in[4];
    const float* w1r  = (const float*)d_in[5];
    const float* w1i  = (const float*)d_in[6];
    const float* w2r  = (const float*)d_in[7];
    const float* w2i  = (const float*)d_in[8];
    const float* q_w  = (const float*)d_in[9];
    const float* q_b  = (const float*)d_in[10];
    float* out = (float*)d_out;

    float* h = (float*)d_ws;
    float* A = h + (size_t)NB * DV * SS * SS;
    float* F = A + (size_t)NB * MM * DV * SS * 2;

    dim3 blk(256);
    k_lift<<<NB * SS, blk, 0, stream>>>(x, p_w, p_b, h);
    for (int l = 0; l < LL; ++l) {
        k_rowdft<<<NB * DV, blk, 0, stream>>>(h, A);
        k_mix<<<NB * MM, blk, 0, stream>>>(A, w1r, w1i, w2r, w2i, F, l);
        if (l < LL - 1)
            k_pt<0><<<NB * SS, blk, 0, stream>>>(h, F, ws_w, ws_b,
                                                 nullptr, nullptr, nullptr, l);
        else
            k_pt<1><<<NB * SS, blk, 0, stream>>>(h, F, ws_w, ws_b,
                                                 q_w, q_b, out, l);
    }
}